// Round 16
// baseline (99.350 us; speedup 1.0000x reference)
//
#include <hip/hip_runtime.h>

typedef __attribute__((ext_vector_type(8))) short bf16x8;
typedef __attribute__((ext_vector_type(4))) float f32x4;

__device__ __forceinline__ unsigned short f2bf(float f) {
    unsigned u = __float_as_uint(f);
    unsigned r = (u + 0x7FFFu + ((u >> 16) & 1u)) >> 16;   // RNE
    return (unsigned short)r;
}

__device__ __forceinline__ void gload16(const unsigned short* g, unsigned short* l) {
    __builtin_amdgcn_global_load_lds((const __attribute__((address_space(1))) void*)g,
                                     (__attribute__((address_space(3))) void*)l, 16, 0, 0);
}

#define BARRIER() do { asm volatile("" ::: "memory"); __builtin_amdgcn_s_barrier(); asm volatile("" ::: "memory"); } while (0)

// ---------------- fused prep: conv_x + conv_c + c2 + packed-init ----------------
__global__ void prep_kernel(const float* __restrict__ x, unsigned short* __restrict__ xb,
                            const float* __restrict__ c, unsigned short* __restrict__ cb,
                            float* __restrict__ c2, unsigned long long* __restrict__ packed,
                            int total8, int nxb, int N, int D) {
    const int bid = blockIdx.x;
    const int tid = threadIdx.x;
    if (bid < nxb) {
        int i = bid * 256 + tid;
        if (i >= total8) return;
        const float4* xv = (const float4*)x;
        float4 a = xv[(size_t)i * 2];
        float4 b = xv[(size_t)i * 2 + 1];
        uint4 o;
        o.x = (unsigned)f2bf(a.x) | ((unsigned)f2bf(a.y) << 16);
        o.y = (unsigned)f2bf(a.z) | ((unsigned)f2bf(a.w) << 16);
        o.z = (unsigned)f2bf(b.x) | ((unsigned)f2bf(b.y) << 16);
        o.w = (unsigned)f2bf(b.z) | ((unsigned)f2bf(b.w) << 16);
        ((uint4*)xb)[i] = o;
        return;
    }
    const int k = bid - nxb;
    const float4 v = ((const float4*)(c + (long)k * D))[tid];
    uint2 o;
    o.x = (unsigned)f2bf(v.x) | ((unsigned)f2bf(v.y) << 16);
    o.y = (unsigned)f2bf(v.z) | ((unsigned)f2bf(v.w) << 16);
    ((uint2*)(cb + (long)k * D))[tid] = o;
    float s = v.x * v.x + v.y * v.y + v.z * v.z + v.w * v.w;
    #pragma unroll
    for (int d = 1; d < 64; d <<= 1) s += __shfl_xor(s, d, 64);
    __shared__ float wsum[4];
    int lane = tid & 63, w = tid >> 6;
    if (lane == 0) wsum[w] = s;
    __syncthreads();
    if (tid == 0) c2[k] = wsum[0] + wsum[1] + wsum[2] + wsum[3];
    int gid = k * 256 + tid;
    if (gid < N) packed[gid] = ~0ull;
}

// ------------- GEMM + argmin : 256x128 tile, K-step 32, ring-of-3, 2 blocks/CU -------------
// LDS 72 KiB (<=80 -> two blocks co-resident): A slot s = ushort[s*8192, +8192)
// (256 rows x 32 k), B slot = ushort[24576 + s*4096, +4096) (128 rows x 32 k).
// 8 waves as 4x2: wave (wr=w>>1, wc=w&1) owns 64x64 out; acc[4][4] = 64 AGPR,
// a[4]+b[4] frags -> fits the 128-reg budget of __launch_bounds__(512,4).
// Per tile t: { stage(t+2) [2 A-chunks + 1 B-chunk/thread]; ds_read a[4],b[4]
// from slot t%3; s_waitcnt vmcnt(K) lgkmcnt(0); BARRIER; 16 MFMA } -- no
// post-MFMA barrier (r6 slip).  vmcnt K = 3 x stages-ahead: 6 / 3 / 0 at the
// tail (proves stage(t) retired per-wave BEFORE the barrier; barrier then makes
// it cross-wave -- fixes r6's benign tail race).  WAR: lgkmcnt(0) pre-BARRIER
// retires reads of slot (t-1)%3; stage(t+2) targets it only after the BARRIER.
// Mechanism sought: with 2 independent blocks per CU, one block's staging
// overlaps the other's MFMA (m114 TLP) -- the V2-ablation showed staging is
// the only non-overlapping term (1183 of 3240 cyc/tile) at 1 block/CU.
__global__ void __launch_bounds__(512, 4)
gemm_argmin_kernel(const unsigned short* __restrict__ Xb,
                   const unsigned short* __restrict__ Cb,
                   const float* __restrict__ c2,
                   unsigned long long* __restrict__ packed,
                   int D, int nt) {
    __shared__ unsigned short sh[36864];       // 72 KiB
    const int tid  = threadIdx.x;
    const int lane = tid & 63;
    const int w    = tid >> 6;                 // 0..7
    const int wr   = w >> 1;                   // 0..3 : rows wr*64..+63
    const int wc   = w & 1;                    // 0..1 : cols wc*64..+63
    const long rowbase = (long)blockIdx.x * 256;
    const int  colbase = blockIdx.y * 128;
    const int fr = lane & 15;
    const int g  = lane >> 4;

    // staging: A chunks c0=tid, c1=512+tid (row=c>>2, 16B slot q=c&3);
    //          B chunk  c=tid (row=tid>>2, q=tid&3)
    const int c0 = tid, c1 = 512 + tid;
    const unsigned short* gA0 = Xb + (rowbase + (c0 >> 2)) * D + (c0 & 3) * 8;
    const unsigned short* gA1 = Xb + (rowbase + (c1 >> 2)) * D + (c1 & 3) * 8;
    const unsigned short* gB0 = Cb + ((long)colbase + (tid >> 2)) * D + (tid & 3) * 8;

    f32x4 acc[4][4] = {};
    bf16x8 a[4], b[4];

    auto stage = [&](int kt) {
        const int s = kt % 3;
        const long ko = (long)kt * 32;
        gload16(gA0 + ko, sh + s * 8192 + c0 * 8);
        gload16(gA1 + ko, sh + s * 8192 + c1 * 8);
        gload16(gB0 + ko, sh + 24576 + s * 4096 + tid * 8);
    };

    // prologue: slots 0,1; vmcnt(3) leaves only stage(1) -> stage(0) retired
    stage(0); stage(1);
    asm volatile("s_waitcnt vmcnt(3)" ::: "memory");
    BARRIER();

    for (int t = 0; t < nt; ++t) {
        const int s = t % 3;
        const int ar = s * 8192 + (wr * 64 + fr) * 32 + g * 8;
        const int br = 24576 + s * 4096 + (wc * 64 + fr) * 32 + g * 8;
        if (t + 2 < nt) stage(t + 2);
        #pragma unroll
        for (int m = 0; m < 4; ++m) a[m] = *(const bf16x8*)&sh[ar + m * 512];
        #pragma unroll
        for (int n = 0; n < 4; ++n) b[n] = *(const bf16x8*)&sh[br + n * 512];
        if (t + 2 < nt)      asm volatile("s_waitcnt vmcnt(6) lgkmcnt(0)" ::: "memory");
        else if (t + 1 < nt) asm volatile("s_waitcnt vmcnt(3) lgkmcnt(0)" ::: "memory");
        else                 asm volatile("s_waitcnt vmcnt(0) lgkmcnt(0)" ::: "memory");
        BARRIER();
        __builtin_amdgcn_s_setprio(1);
        #pragma unroll
        for (int m = 0; m < 4; ++m)
            #pragma unroll
            for (int n = 0; n < 4; ++n)
                acc[m][n] = __builtin_amdgcn_mfma_f32_16x16x32_bf16(a[m], b[n], acc[m][n], 0, 0, 0);
        __builtin_amdgcn_s_setprio(0);
        // no post-MFMA barrier: waves slip into next tile's reads/stages.
    }

    // ---- argmin epilogue: score = c2[k] - 2*dot.  C/D: col=lane&15, row=g*4+reg ----
    float c2v[4];
    int   kcol[4];
    #pragma unroll
    for (int n = 0; n < 4; ++n) {
        kcol[n] = colbase + wc * 64 + n * 16 + fr;
        c2v[n]  = c2[kcol[n]];
    }
    #pragma unroll
    for (int m = 0; m < 4; ++m) {
        #pragma unroll
        for (int reg = 0; reg < 4; ++reg) {
            unsigned long long best = ~0ull;
            #pragma unroll
            for (int n = 0; n < 4; ++n) {
                float score = c2v[n] - 2.0f * acc[m][n][reg];
                unsigned u = __float_as_uint(score);
                u ^= (u >> 31) ? 0xFFFFFFFFu : 0x80000000u;   // order-preserving map
                unsigned long long cand = ((unsigned long long)u << 32) | (unsigned)kcol[n];
                best = cand < best ? cand : best;
            }
            #pragma unroll
            for (int s2 = 1; s2 < 16; s2 <<= 1) {
                unsigned long long other = __shfl_xor(best, s2, 64);
                best = other < best ? other : best;
            }
            if (fr == 0) {
                long row = rowbase + wr * 64 + m * 16 + g * 4 + reg;
                atomicMin(&packed[row], best);   // min is order-independent -> deterministic
            }
        }
    }
}

// ---------------- segmented sum: sliced partials (S=4, MLP-4 gather) ----------------
__global__ void segsum_partial_kernel(const unsigned long long* __restrict__ packed,
                                      const float* __restrict__ emb,
                                      float* __restrict__ partial,
                                      int* __restrict__ pcount,
                                      int N, int D) {
    const int k   = blockIdx.x;
    const int s   = blockIdx.y;
    const int tid = threadIdx.x;
    const int grp = tid >> 8;
    const int ct  = tid & 255;
    const int lane = tid & 63, w = tid >> 6;

    __shared__ int idxbuf[4096];
    __shared__ int cnts[16];
    __shared__ float4 red[4][256];

    const int slice = N >> 2;             // 4096
    const int base0 = s * slice;
    int total = 0;
    for (int base = base0; base < base0 + slice; base += 1024) {
        const int n = base + tid;
        const bool m = ((unsigned)(packed[n] & 0xFFFFFFFFull) == (unsigned)k);
        const unsigned long long bal = __ballot(m);
        if (lane == 0) cnts[w] = (int)__popcll(bal);
        __syncthreads();
        int myoff = total, run = total;
        #pragma unroll
        for (int w2 = 0; w2 < 16; ++w2) {
            if (w2 == w) myoff = run;
            run += cnts[w2];
        }
        if (m) idxbuf[myoff + (int)__popcll(bal & ((1ull << lane) - 1ull))] = n;
        total = run;
        __syncthreads();
    }

    const long ctoff = (long)ct * 4;
    float4 a0 = {0.f,0.f,0.f,0.f}, a1 = {0.f,0.f,0.f,0.f};
    float4 a2 = {0.f,0.f,0.f,0.f}, a3 = {0.f,0.f,0.f,0.f};
    int j = grp;
    for (; j + 12 < total; j += 16) {
        const int r0 = idxbuf[j];
        const int r1 = idxbuf[j + 4];
        const int r2 = idxbuf[j + 8];
        const int r3 = idxbuf[j + 12];
        const float4 v0 = *(const float4*)(emb + (long)r0 * D + ctoff);
        const float4 v1 = *(const float4*)(emb + (long)r1 * D + ctoff);
        const float4 v2 = *(const float4*)(emb + (long)r2 * D + ctoff);
        const float4 v3 = *(const float4*)(emb + (long)r3 * D + ctoff);
        a0.x += v0.x; a0.y += v0.y; a0.z += v0.z; a0.w += v0.w;
        a1.x += v1.x; a1.y += v1.y; a1.z += v1.z; a1.w += v1.w;
        a2.x += v2.x; a2.y += v2.y; a2.z += v2.z; a2.w += v2.w;
        a3.x += v3.x; a3.y += v3.y; a3.z += v3.z; a3.w += v3.w;
    }
    for (; j < total; j += 4) {
        const float4 v = *(const float4*)(emb + (long)idxbuf[j] * D + ctoff);
        a0.x += v.x; a0.y += v.y; a0.z += v.z; a0.w += v.w;
    }
    float4 acc;
    acc.x = (a0.x + a1.x) + (a2.x + a3.x);
    acc.y = (a0.y + a1.y) + (a2.y + a3.y);
    acc.z = (a0.z + a1.z) + (a2.z + a3.z);
    acc.w = (a0.w + a1.w) + (a2.w + a3.w);

    red[grp][ct] = acc;
    __syncthreads();
    if (grp == 0) {
        float4 r = red[0][ct];
        #pragma unroll
        for (int q = 1; q < 4; ++q) {
            const float4 v = red[q][ct];
            r.x += v.x; r.y += v.y; r.z += v.z; r.w += v.w;
        }
        *(float4*)(partial + ((long)(k * 4 + s)) * D + ctoff) = r;
    }
    if (tid == 0) pcount[k * 4 + s] = total;
}

// one block per cluster: reduce 4 slice partials (fixed order) + EMA finalize
__global__ void finalize_kernel(const float* __restrict__ partial,
                                const int* __restrict__ pcount,
                                const float* __restrict__ centers,
                                const int* __restrict__ cnt,
                                float* __restrict__ out, int D) {
    const int k = blockIdx.x;
    const int ct = threadIdx.x;           // 256 threads, 4 cols each
    float4 acc = {0.f, 0.f, 0.f, 0.f};
    int mtot = 0;
    #pragma unroll
    for (int s = 0; s < 4; ++s) {
        const float4 p = *(const float4*)(partial + ((long)(k * 4 + s)) * D + ct * 4);
        acc.x += p.x; acc.y += p.y; acc.z += p.z; acc.w += p.w;
        mtot += pcount[k * 4 + s];
    }
    const float4 cv = *(const float4*)(centers + (long)k * D + ct * 4);
    float4 o;
    if (mtot > 0) {
        float ccn = 0.5f * (float)cnt[k] + 0.5f * (float)mtot;
        float lr  = 1.0f / (ccn + 1.0f);
        float im  = 1.0f / (float)mtot;
        float om  = 1.0f - lr;
        o.x = om * cv.x + lr * (acc.x * im);
        o.y = om * cv.y + lr * (acc.y * im);
        o.z = om * cv.z + lr * (acc.z * im);
        o.w = om * cv.w + lr * (acc.w * im);
    } else {
        o = cv;
    }
    *(float4*)(out + (long)k * D + ct * 4) = o;
}

// ---------------- launch ----------------

extern "C" void kernel_launch(void* const* d_in, const int* in_sizes, int n_in,
                              void* d_out, int out_size, void* d_ws, size_t ws_size,
                              hipStream_t stream) {
    const float* emb = (const float*)d_in[0];
    const float* cen = (const float*)d_in[1];
    const int*   cnt = (const int*)d_in[2];
    float* out = (float*)d_out;
    const int K = in_sizes[2];
    const int D = in_sizes[1] / K;      // 1024
    const int N = in_sizes[0] / D;      // 16384

    char* ws = (char*)d_ws;
    size_t xb_bytes = (size_t)N * D * 2;            // 32 MB
    size_t cb_bytes = (size_t)K * D * 2;            // 2 MB
    unsigned short* Xb = (unsigned short*)ws;
    unsigned short* Cb = (unsigned short*)(ws + xb_bytes);
    float* c2 = (float*)(ws + xb_bytes + cb_bytes);
    unsigned long long* packed = (unsigned long long*)(ws + xb_bytes + cb_bytes + (size_t)K * 4);
    int* pcount = (int*)(ws + xb_bytes + cb_bytes + (size_t)K * 4 + (size_t)N * 8);
    // partial [K][4][D] fp32 = 16 MB aliases the Xb region (dead after gemm).
    float* partial = (float*)ws;

    const int total8 = N * D / 8;                   // 2M
    const int nxb = (total8 + 255) / 256;           // 8192
    prep_kernel<<<dim3(nxb + K), dim3(256), 0, stream>>>(emb, Xb, cen, Cb, c2, packed, total8, nxb, N, D);
    gemm_argmin_kernel<<<dim3(N / 256, K / 128), dim3(512), 0, stream>>>(Xb, Cb, c2, packed, D, D / 32);
    segsum_partial_kernel<<<dim3(K, 4), dim3(1024), 0, stream>>>(packed, emb, partial, pcount, N, D);
    finalize_kernel<<<dim3(K), dim3(256), 0, stream>>>(partial, pcount, cen, cnt, out, D);
}

// Round 17
// 96.285 us; speedup vs baseline: 1.0318x; 1.0318x over previous
//
#include <hip/hip_runtime.h>

typedef __attribute__((ext_vector_type(8))) short bf16x8;
typedef __attribute__((ext_vector_type(4))) float f32x4;

__device__ __forceinline__ unsigned short f2bf(float f) {
    unsigned u = __float_as_uint(f);
    unsigned r = (u + 0x7FFFu + ((u >> 16) & 1u)) >> 16;   // RNE
    return (unsigned short)r;
}

__device__ __forceinline__ void gload16(const unsigned short* g, unsigned short* l) {
    __builtin_amdgcn_global_load_lds((const __attribute__((address_space(1))) void*)g,
                                     (__attribute__((address_space(3))) void*)l, 16, 0, 0);
}

#define BARRIER() do { asm volatile("" ::: "memory"); __builtin_amdgcn_s_barrier(); asm volatile("" ::: "memory"); } while (0)

// ---------------- fused prep: conv_x + conv_c + c2 + packed-init ----------------
__global__ void prep_kernel(const float* __restrict__ x, unsigned short* __restrict__ xb,
                            const float* __restrict__ c, unsigned short* __restrict__ cb,
                            float* __restrict__ c2, unsigned long long* __restrict__ packed,
                            int total8, int nxb, int N, int D) {
    const int bid = blockIdx.x;
    const int tid = threadIdx.x;
    if (bid < nxb) {
        int i = bid * 256 + tid;
        if (i >= total8) return;
        const float4* xv = (const float4*)x;
        float4 a = xv[(size_t)i * 2];
        float4 b = xv[(size_t)i * 2 + 1];
        uint4 o;
        o.x = (unsigned)f2bf(a.x) | ((unsigned)f2bf(a.y) << 16);
        o.y = (unsigned)f2bf(a.z) | ((unsigned)f2bf(a.w) << 16);
        o.z = (unsigned)f2bf(b.x) | ((unsigned)f2bf(b.y) << 16);
        o.w = (unsigned)f2bf(b.z) | ((unsigned)f2bf(b.w) << 16);
        ((uint4*)xb)[i] = o;
        return;
    }
    const int k = bid - nxb;
    const float4 v = ((const float4*)(c + (long)k * D))[tid];
    uint2 o;
    o.x = (unsigned)f2bf(v.x) | ((unsigned)f2bf(v.y) << 16);
    o.y = (unsigned)f2bf(v.z) | ((unsigned)f2bf(v.w) << 16);
    ((uint2*)(cb + (long)k * D))[tid] = o;
    float s = v.x * v.x + v.y * v.y + v.z * v.z + v.w * v.w;
    #pragma unroll
    for (int d = 1; d < 64; d <<= 1) s += __shfl_xor(s, d, 64);
    __shared__ float wsum[4];
    int lane = tid & 63, w = tid >> 6;
    if (lane == 0) wsum[w] = s;
    __syncthreads();
    if (tid == 0) c2[k] = wsum[0] + wsum[1] + wsum[2] + wsum[3];
    int gid = k * 256 + tid;
    if (gid < N) packed[gid] = ~0ull;
}

// ------------- GEMM + argmin (ring-of-4, 256x256, BK=32 -- best known 43.2us) -------------
// Plateau characterization (r3-r16): MFMA floor 2048 cyc/tile + ~1183 cyc
// serialized global_load_lds write throughput (~28 B/cyc for 32 KB/tile).
// Invariant to: schedule (5 variants), LDS swizzle, occupancy (1 vs 2
// blocks/CU), byte width (fp8 regressed via bank conflicts), reg-staging
// (regressed).  This is the decomposition's structural floor.
__global__ void __launch_bounds__(512, 2)
gemm_argmin_kernel(const unsigned short* __restrict__ Xb,
                   const unsigned short* __restrict__ Cb,
                   const float* __restrict__ c2,
                   unsigned long long* __restrict__ packed,
                   int D, int nt) {
    __shared__ unsigned short sh[65536];       // 128 KiB
    const int tid  = threadIdx.x;
    const int lane = tid & 63;
    const int w    = tid >> 6;
    const int wr   = w >> 2;
    const int wc   = w & 3;
    const long rowbase = (long)blockIdx.x * 256;
    const int  colbase = blockIdx.y * 256;
    const int fr = lane & 15;
    const int g  = lane >> 4;

    const int c0 = tid, c1 = 512 + tid;
    const unsigned short* gA0 = Xb + (rowbase + (c0 >> 2)) * D + (c0 & 3) * 8;
    const unsigned short* gA1 = Xb + (rowbase + (c1 >> 2)) * D + (c1 & 3) * 8;
    const unsigned short* gB0 = Cb + ((long)colbase + (c0 >> 2)) * D + (c0 & 3) * 8;
    const unsigned short* gB1 = Cb + ((long)colbase + (c1 >> 2)) * D + (c1 & 3) * 8;

    f32x4 acc[8][4] = {};
    bf16x8 a[8], b[4];

    auto stage = [&](int kt) {
        const int s = (kt & 3) * 8192;
        const long ko = (long)kt * 32;
        gload16(gA0 + ko, sh + s + c0 * 8);
        gload16(gA1 + ko, sh + s + c1 * 8);
        gload16(gB0 + ko, sh + 32768 + s + c0 * 8);
        gload16(gB1 + ko, sh + 32768 + s + c1 * 8);
    };

    stage(0); stage(1); stage(2);
    asm volatile("s_waitcnt vmcnt(8)" ::: "memory");
    BARRIER();

    for (int t = 0; t < nt; ++t) {
        const int sb = (t & 3) * 8192;
        if (t + 3 < nt) stage(t + 3);
        const int ar = sb + (wr * 128 + fr) * 32 + g * 8;
        #pragma unroll
        for (int m = 0; m < 8; ++m) a[m] = *(const bf16x8*)&sh[ar + m * 512];
        const int br = 32768 + sb + (wc * 64 + fr) * 32 + g * 8;
        #pragma unroll
        for (int n = 0; n < 4; ++n) b[n] = *(const bf16x8*)&sh[br + n * 512];
        asm volatile("s_waitcnt vmcnt(8) lgkmcnt(0)" ::: "memory");
        BARRIER();
        __builtin_amdgcn_s_setprio(1);
        #pragma unroll
        for (int m = 0; m < 8; ++m)
            #pragma unroll
            for (int n = 0; n < 4; ++n)
                acc[m][n] = __builtin_amdgcn_mfma_f32_16x16x32_bf16(a[m], b[n], acc[m][n], 0, 0, 0);
        __builtin_amdgcn_s_setprio(0);
    }

    float c2v[4];
    int   kcol[4];
    #pragma unroll
    for (int n = 0; n < 4; ++n) {
        kcol[n] = colbase + wc * 64 + n * 16 + fr;
        c2v[n]  = c2[kcol[n]];
    }
    #pragma unroll
    for (int m = 0; m < 8; ++m) {
        #pragma unroll
        for (int reg = 0; reg < 4; ++reg) {
            unsigned long long best = ~0ull;
            #pragma unroll
            for (int n = 0; n < 4; ++n) {
                float score = c2v[n] - 2.0f * acc[m][n][reg];
                unsigned u = __float_as_uint(score);
                u ^= (u >> 31) ? 0xFFFFFFFFu : 0x80000000u;   // order-preserving map
                unsigned long long cand = ((unsigned long long)u << 32) | (unsigned)kcol[n];
                best = cand < best ? cand : best;
            }
            #pragma unroll
            for (int s = 1; s < 16; s <<= 1) {
                unsigned long long other = __shfl_xor(best, s, 64);
                best = other < best ? other : best;
            }
            if (fr == 0) {
                long row = rowbase + wr * 128 + m * 16 + g * 4 + reg;
                atomicMin(&packed[row], best);   // min is order-independent -> deterministic
            }
        }
    }
}

// ---------------- segmented sum: sliced partials (S=4, MLP-4 gather) ----------------
__global__ void segsum_partial_kernel(const unsigned long long* __restrict__ packed,
                                      const float* __restrict__ emb,
                                      float* __restrict__ partial,
                                      int* __restrict__ pcount,
                                      int N, int D) {
    const int k   = blockIdx.x;
    const int s   = blockIdx.y;
    const int tid = threadIdx.x;
    const int grp = tid >> 8;
    const int ct  = tid & 255;
    const int lane = tid & 63, w = tid >> 6;

    __shared__ int idxbuf[4096];
    __shared__ int cnts[16];
    __shared__ float4 red[4][256];

    const int slice = N >> 2;             // 4096
    const int base0 = s * slice;
    int total = 0;
    for (int base = base0; base < base0 + slice; base += 1024) {
        const int n = base + tid;
        const bool m = ((unsigned)(packed[n] & 0xFFFFFFFFull) == (unsigned)k);
        const unsigned long long bal = __ballot(m);
        if (lane == 0) cnts[w] = (int)__popcll(bal);
        __syncthreads();
        int myoff = total, run = total;
        #pragma unroll
        for (int w2 = 0; w2 < 16; ++w2) {
            if (w2 == w) myoff = run;
            run += cnts[w2];
        }
        if (m) idxbuf[myoff + (int)__popcll(bal & ((1ull << lane) - 1ull))] = n;
        total = run;
        __syncthreads();
    }

    const long ctoff = (long)ct * 4;
    float4 a0 = {0.f,0.f,0.f,0.f}, a1 = {0.f,0.f,0.f,0.f};
    float4 a2 = {0.f,0.f,0.f,0.f}, a3 = {0.f,0.f,0.f,0.f};
    int j = grp;
    for (; j + 12 < total; j += 16) {
        const int r0 = idxbuf[j];
        const int r1 = idxbuf[j + 4];
        const int r2 = idxbuf[j + 8];
        const int r3 = idxbuf[j + 12];
        const float4 v0 = *(const float4*)(emb + (long)r0 * D + ctoff);
        const float4 v1 = *(const float4*)(emb + (long)r1 * D + ctoff);
        const float4 v2 = *(const float4*)(emb + (long)r2 * D + ctoff);
        const float4 v3 = *(const float4*)(emb + (long)r3 * D + ctoff);
        a0.x += v0.x; a0.y += v0.y; a0.z += v0.z; a0.w += v0.w;
        a1.x += v1.x; a1.y += v1.y; a1.z += v1.z; a1.w += v1.w;
        a2.x += v2.x; a2.y += v2.y; a2.z += v2.z; a2.w += v2.w;
        a3.x += v3.x; a3.y += v3.y; a3.z += v3.z; a3.w += v3.w;
    }
    for (; j < total; j += 4) {
        const float4 v = *(const float4*)(emb + (long)idxbuf[j] * D + ctoff);
        a0.x += v.x; a0.y += v.y; a0.z += v.z; a0.w += v.w;
    }
    float4 acc;
    acc.x = (a0.x + a1.x) + (a2.x + a3.x);
    acc.y = (a0.y + a1.y) + (a2.y + a3.y);
    acc.z = (a0.z + a1.z) + (a2.z + a3.z);
    acc.w = (a0.w + a1.w) + (a2.w + a3.w);

    red[grp][ct] = acc;
    __syncthreads();
    if (grp == 0) {
        float4 r = red[0][ct];
        #pragma unroll
        for (int q = 1; q < 4; ++q) {
            const float4 v = red[q][ct];
            r.x += v.x; r.y += v.y; r.z += v.z; r.w += v.w;
        }
        *(float4*)(partial + ((long)(k * 4 + s)) * D + ctoff) = r;
    }
    if (tid == 0) pcount[k * 4 + s] = total;
}

// one block per cluster: reduce 4 slice partials (fixed order) + EMA finalize
__global__ void finalize_kernel(const float* __restrict__ partial,
                                const int* __restrict__ pcount,
                                const float* __restrict__ centers,
                                const int* __restrict__ cnt,
                                float* __restrict__ out, int D) {
    const int k = blockIdx.x;
    const int ct = threadIdx.x;           // 256 threads, 4 cols each
    float4 acc = {0.f, 0.f, 0.f, 0.f};
    int mtot = 0;
    #pragma unroll
    for (int s = 0; s < 4; ++s) {
        const float4 p = *(const float4*)(partial + ((long)(k * 4 + s)) * D + ct * 4);
        acc.x += p.x; acc.y += p.y; acc.z += p.z; acc.w += p.w;
        mtot += pcount[k * 4 + s];
    }
    const float4 cv = *(const float4*)(centers + (long)k * D + ct * 4);
    float4 o;
    if (mtot > 0) {
        float ccn = 0.5f * (float)cnt[k] + 0.5f * (float)mtot;
        float lr  = 1.0f / (ccn + 1.0f);
        float im  = 1.0f / (float)mtot;
        float om  = 1.0f - lr;
        o.x = om * cv.x + lr * (acc.x * im);
        o.y = om * cv.y + lr * (acc.y * im);
        o.z = om * cv.z + lr * (acc.z * im);
        o.w = om * cv.w + lr * (acc.w * im);
    } else {
        o = cv;
    }
    *(float4*)(out + (long)k * D + ct * 4) = o;
}

// ---------------- launch ----------------

extern "C" void kernel_launch(void* const* d_in, const int* in_sizes, int n_in,
                              void* d_out, int out_size, void* d_ws, size_t ws_size,
                              hipStream_t stream) {
    const float* emb = (const float*)d_in[0];
    const float* cen = (const float*)d_in[1];
    const int*   cnt = (const int*)d_in[2];
    float* out = (float*)d_out;
    const int K = in_sizes[2];
    const int D = in_sizes[1] / K;      // 1024
    const int N = in_sizes[0] / D;      // 16384

    char* ws = (char*)d_ws;
    size_t xb_bytes = (size_t)N * D * 2;            // 32 MB
    size_t cb_bytes = (size_t)K * D * 2;            // 2 MB
    unsigned short* Xb = (unsigned short*)ws;
    unsigned short* Cb = (unsigned short*)(ws + xb_bytes);
    float* c2 = (float*)(ws + xb_bytes + cb_bytes);
    unsigned long long* packed = (unsigned long long*)(ws + xb_bytes + cb_bytes + (size_t)K * 4);
    int* pcount = (int*)(ws + xb_bytes + cb_bytes + (size_t)K * 4 + (size_t)N * 8);
    // partial [K][4][D] fp32 = 16 MB aliases the Xb region (dead after gemm).
    float* partial = (float*)ws;

    const int total8 = N * D / 8;                   // 2M
    const int nxb = (total8 + 255) / 256;           // 8192
    prep_kernel<<<dim3(nxb + K), dim3(256), 0, stream>>>(emb, Xb, cen, Cb, c2, packed, total8, nxb, N, D);
    gemm_argmin_kernel<<<dim3(N / 256, K / 256), dim3(512), 0, stream>>>(Xb, Cb, c2, packed, D, D / 32);
    segsum_partial_kernel<<<dim3(K, 4), dim3(1024), 0, stream>>>(packed, emb, partial, pcount, N, D);
    finalize_kernel<<<dim3(K), dim3(256), 0, stream>>>(partial, pcount, cen, cnt, out, D);
}